// Round 4
// baseline (203.858 us; speedup 1.0000x reference)
//
#include <hip/hip_runtime.h>
#include <hip/hip_bf16.h>
#include <cstdint>

#define BATCH 4096
#define INF   1024
#define OUTF  1024
#define LCH   12              // 11 spline channels + 1 base channel
#define KTOT  (INF*LCH)       // 12288

#define BM 128
#define BN 128
#define IC 8                  // input features per chunk
#define BK (IC*LCH)           // 96 k per chunk
#define NCHUNK (INF/IC)       // 128
#define NGRAN 12              // 8-elem granules per chunk (per row/col)
#define THREADS 512
#define BUFSZ (NGRAN*128*8)   // 12288 ushorts per tile buffer

typedef __bf16 bf16x8 __attribute__((ext_vector_type(8)));
typedef float  f32x16 __attribute__((ext_vector_type(16)));
typedef unsigned long long ull;

struct alignas(16) U2 { ull x, y; };

__device__ __forceinline__ unsigned short f2bf(float f) {
  unsigned int u = __builtin_bit_cast(unsigned int, f);
  u += 0x7FFFu + ((u >> 16) & 1u);
  return (unsigned short)(u >> 16);
}

__device__ __forceinline__ void async_copy16(const void* g, void* l) {
  __builtin_amdgcn_global_load_lds(
      (const __attribute__((address_space(1))) unsigned int*)g,
      (__attribute__((address_space(3))) unsigned int*)l,
      16, 0, 0);
}

// counted-vmcnt pipeline barrier: keep the newest 4 VMEM ops (this iter's
// x-load + 3 B-DMAs) in flight; drain older ones + all LDS ops.
#define PIPE_BARRIER() do {                                        \
  asm volatile("s_waitcnt vmcnt(4) lgkmcnt(0)" ::: "memory");      \
  __builtin_amdgcn_sched_barrier(0);                               \
  __builtin_amdgcn_s_barrier();                                    \
  __builtin_amdgcn_sched_barrier(0);                               \
} while (0)

// ---------------- kernel 1: weights f32 -> bf16, k = i*12 + l ----------------
__global__ __launch_bounds__(256) void kan_build_wt(
    const float* __restrict__ sw,        // [OUTF][INF][11]
    const float* __restrict__ bw,        // [OUTF][INF]
    unsigned short* __restrict__ Wt)     // [OUTF][KTOT] bf16
{
  int idx = blockIdx.x * 256 + threadIdx.x;
  int o = idx >> 10;
  int i = idx & 1023;
  const float* s = sw + (size_t)(o * 1024 + i) * 11;
  unsigned short v[12];
#pragma unroll
  for (int l = 0; l < 11; ++l) v[l] = f2bf(s[l]);
  v[11] = f2bf(bw[o * 1024 + i]);
  unsigned short* d = Wt + (size_t)o * KTOT + i * 12;
  *reinterpret_cast<ushort4*>(d + 0) = make_ushort4(v[0], v[1], v[2],  v[3]);
  *reinterpret_cast<ushort4*>(d + 4) = make_ushort4(v[4], v[5], v[6],  v[7]);
  *reinterpret_cast<ushort4*>(d + 8) = make_ushort4(v[8], v[9], v[10], v[11]);
}

// ---------------- kernel 2: fused basis-build + 32x32 MFMA GEMM, K-split ----
__global__ __launch_bounds__(THREADS, 1) void kan_gemm(
    const float* __restrict__ x,             // [BATCH][INF]
    const unsigned short* __restrict__ Wt,   // [OUTF][KTOT] bf16
    float* __restrict__ out)                 // [BATCH][OUTF]
{
  // 3 B buffers + 2 A buffers, all [NGRAN][128][8] granule-interleaved
  __shared__ alignas(16) unsigned short smem[5 * BUFSZ];   // 122880 B

  const int tid  = threadIdx.x;
  const int lane = tid & 63;
  const int wid  = tid >> 6;              // 0..7
  const int g    = wid >> 2;              // k-group: 0 -> ksteps 0..2, 1 -> 3..5
  const int q    = wid & 3;               // output quadrant
  const int qm   = q >> 1;                // 0,1 -> rows qm*64
  const int qn   = q & 1;                 // 0,1 -> cols qn*64
  const int lo   = lane & 31;
  const int lh   = lane >> 5;
  const int bm   = (int)blockIdx.x >> 3;  // 0..31
  const int bn   = (int)blockIdx.x & 7;   // 0..7

  // A-build mapping: thread -> (row ab, 2 features at ai0)
  const int ab  = tid & 127;              // lane-consecutive rows
  const int ai0 = (tid >> 7) << 1;        // 0,2,4,6 (wave-uniform)
  const float* xrow = x + (size_t)(bm * BM + ab) * INF + ai0;

  unsigned short* Bcur = smem;
  unsigned short* Bnxt = smem + BUFSZ;
  unsigned short* Bnn  = smem + 2 * BUFSZ;
  unsigned short* Acur = smem + 3 * BUFSZ;
  unsigned short* Aalt = smem + 4 * BUFSZ;

  f32x16 acc[2][2] = {};

  auto stageB = [&](int c, unsigned short* Bd) {
#pragma unroll
    for (int qq = 0; qq < 3; ++qq) {
      int G  = (wid * 3 + qq) * 64 + lane;   // granule 0..1535
      int kk = G >> 7;                       // 0..11
      int oo = G & 127;
      const unsigned short* src = Wt + (size_t)(bn * BN + oo) * KTOT + (c * BK + kk * 8);
      async_copy16(src, Bd + (wid * 3 + qq) * 512);   // wave-uniform base; HW adds lane*16
    }
  };

  auto buildA = [&](float2 xv, unsigned short* Ad) {
    ull W[6];
#pragma unroll
    for (int j = 0; j < 2; ++j) {
      float xx = (j == 0) ? xv.x : xv.y;
      float u  = fmaf(xx, 4.0f, 7.0f);       // in (3,11); x in (-1,1)
      float fm = floorf(u);
      int   mi = (int)fm;                    // 3..10
      float t  = u - fm;
      float s  = 1.0f - t;
      float t2 = t * t, t3 = t2 * t;
      float w0 = (s * s * s) * (1.0f / 6.0f);
      float w3 = t3 * (1.0f / 6.0f);
      float w1 = fmaf(0.5f, t3, 2.0f / 3.0f) - t2;
      float w2 = 1.0f - w0 - w1 - w3;
      int ls = mi - 3;                       // 0..7

      ull W64 = (ull)f2bf(w0)
              | ((ull)f2bf(w1) << 16)
              | ((ull)f2bf(w2) << 32)
              | ((ull)f2bf(w3) << 48);
      int sh = ls << 4;                      // 0..112
      int a  = sh & 63;
      ull lop = W64 << a;
      ull hip_ = a ? (W64 >> (64 - a)) : 0ull;
      W[3 * j + 0] = (sh < 64) ? lop : 0ull;
      W[3 * j + 1] = (sh < 64) ? hip_ : lop;
      W[3 * j + 2] = ((sh < 64) ? 0ull : hip_) | ((ull)f2bf(xx) << 48); // slot 11 = x
    }
    // write 3 granules (24 k) at rows of granule-interleaved A: [kk][row][8]
    U2* p = reinterpret_cast<U2*>(Ad);
    const int g0 = (ai0 >> 1) * 3;           // 0,3,6,9
    U2 u0; u0.x = W[0]; u0.y = W[1];
    U2 u1; u1.x = W[2]; u1.y = W[3];
    U2 u2; u2.x = W[4]; u2.y = W[5];
    p[(g0 + 0) * 128 + ab] = u0;             // lane-consecutive -> conflict-free
    p[(g0 + 1) * 128 + ab] = u1;
    p[(g0 + 2) * 128 + ab] = u2;
  };

  // ---- prologue ----
  float2 x0v = *reinterpret_cast<const float2*>(xrow);        // chunk 0
  stageB(0, Bcur);
  buildA(x0v, Acur);
  float2 xa = *reinterpret_cast<const float2*>(xrow + IC);    // chunk 1
  stageB(1, Bnxt);
  PIPE_BARRIER();   // drains B0 DMAs + A0 writes; keeps {xa, B1 DMAs} in flight

  const int g3 = g * 3;

  for (int c = 0; c < NCHUNK; ++c) {
    int cf = (c + 2 < NCHUNK) ? (c + 2) : (NCHUNK - 1);
    float2 xb = *reinterpret_cast<const float2*>(xrow + cf * IC);
    stageB(cf, Bnn);
    buildA(xa, Aalt);          // chunk c+1 basis

    // ---- MFMA: this wave's 3 ksteps of 16 (k-split) ----
#pragma unroll
    for (int s = 0; s < 3; ++s) {
      const int kk = (g3 + s) * 2 + lh;     // granule 0..11
      bf16x8 af0 = *reinterpret_cast<const bf16x8*>(&Acur[(kk * 128 + qm * 64 + lo) * 8]);
      bf16x8 af1 = *reinterpret_cast<const bf16x8*>(&Acur[(kk * 128 + qm * 64 + 32 + lo) * 8]);
      bf16x8 bf0 = *reinterpret_cast<const bf16x8*>(&Bcur[(kk * 128 + qn * 64 + lo) * 8]);
      bf16x8 bf1 = *reinterpret_cast<const bf16x8*>(&Bcur[(kk * 128 + qn * 64 + 32 + lo) * 8]);
      acc[0][0] = __builtin_amdgcn_mfma_f32_32x32x16_bf16(af0, bf0, acc[0][0], 0, 0, 0);
      acc[0][1] = __builtin_amdgcn_mfma_f32_32x32x16_bf16(af0, bf1, acc[0][1], 0, 0, 0);
      acc[1][0] = __builtin_amdgcn_mfma_f32_32x32x16_bf16(af1, bf0, acc[1][0], 0, 0, 0);
      acc[1][1] = __builtin_amdgcn_mfma_f32_32x32x16_bf16(af1, bf1, acc[1][1], 0, 0, 0);
    }

    PIPE_BARRIER();

    unsigned short* t = Bcur; Bcur = Bnxt; Bnxt = Bnn; Bnn = t;
    t = Acur; Acur = Aalt; Aalt = t;
    xa = xb;
  }

  // ---- epilogue: merge k-groups via LDS, G0 stores ----
  asm volatile("s_waitcnt vmcnt(0) lgkmcnt(0)" ::: "memory");
  __builtin_amdgcn_s_barrier();            // all DMAs landed; LDS reusable

  float* M = reinterpret_cast<float*>(smem);   // 16384 floats = 64 KB
  if (g == 1) {
#pragma unroll
    for (int mf = 0; mf < 2; ++mf)
#pragma unroll
      for (int nf = 0; nf < 2; ++nf)
#pragma unroll
        for (int r = 0; r < 16; ++r)
          M[(((q * 4 + mf * 2 + nf) * 16 + r) << 6) + lane] = acc[mf][nf][r];
  }
  __syncthreads();
  if (g == 0) {
#pragma unroll
    for (int mf = 0; mf < 2; ++mf) {
#pragma unroll
      for (int nf = 0; nf < 2; ++nf) {
#pragma unroll
        for (int r = 0; r < 16; ++r) {
          float v = acc[mf][nf][r] + M[(((q * 4 + mf * 2 + nf) * 16 + r) << 6) + lane];
          int row = bm * BM + qm * 64 + mf * 32 + (r & 3) + 8 * (r >> 2) + 4 * lh;
          int col = bn * BN + qn * 64 + nf * 32 + lo;
          out[(size_t)row * OUTF + col] = v;
        }
      }
    }
  }
}

extern "C" void kernel_launch(void* const* d_in, const int* in_sizes, int n_in,
                              void* d_out, int out_size, void* d_ws, size_t ws_size,
                              hipStream_t stream) {
  const float* x  = (const float*)d_in[0];   // [4096][1024]
  const float* bw = (const float*)d_in[1];   // [1024][1024]
  const float* sw = (const float*)d_in[2];   // [1024][1024][11]
  float* out = (float*)d_out;

  unsigned short* Wt = (unsigned short*)d_ws;
  if (ws_size < (size_t)OUTF * KTOT * sizeof(unsigned short)) return;

  kan_build_wt<<<(OUTF * INF) / 256, 256, 0, stream>>>(sw, bw, Wt);
  kan_gemm<<<(BATCH / BM) * (OUTF / BN), THREADS, 0, stream>>>(x, Wt, out);
}

// Round 5
// 165.962 us; speedup vs baseline: 1.2283x; 1.2283x over previous
//
#include <hip/hip_runtime.h>
#include <hip/hip_bf16.h>
#include <cstdint>

#define BATCH 4096
#define INF   1024
#define OUTF  1024
#define LCH   12              // 11 spline channels + 1 base channel
#define KTOT  (INF*LCH)       // 12288

#define BM 128
#define BN 128
#define IC 8                  // input features per chunk
#define BK (IC*LCH)           // 96 k per chunk
#define NCHUNK (INF/IC)       // 128
#define NGRAN 12              // 8-elem k-granules per chunk
#define THREADS 512
#define BUFSZ (NGRAN*128*8)   // 12288 ushorts per tile buffer (24 KB)

typedef __bf16 bf16x8 __attribute__((ext_vector_type(8)));
typedef float  f32x4  __attribute__((ext_vector_type(4)));
typedef unsigned long long ull;

struct alignas(16) U2 { ull x, y; };

__device__ __forceinline__ unsigned short f2bf(float f) {
  unsigned int u = __builtin_bit_cast(unsigned int, f);
  u += 0x7FFFu + ((u >> 16) & 1u);
  return (unsigned short)(u >> 16);
}

__device__ __forceinline__ void async_copy16(const void* g, void* l) {
  __builtin_amdgcn_global_load_lds(
      (const __attribute__((address_space(1))) unsigned int*)g,
      (__attribute__((address_space(3))) unsigned int*)l,
      16, 0, 0);
}

// counted-vmcnt pipeline barrier: keep the newest 4 VMEM ops (this iter's
// x-load + 3 B-DMAs) in flight; drain older ones + all LDS ops.
#define PIPE_BARRIER() do {                                        \
  asm volatile("s_waitcnt vmcnt(4) lgkmcnt(0)" ::: "memory");      \
  __builtin_amdgcn_sched_barrier(0);                               \
  __builtin_amdgcn_s_barrier();                                    \
  __builtin_amdgcn_sched_barrier(0);                               \
} while (0)

// ---------------- kernel 1: weights f32 -> bf16, k = i*12 + l ----------------
__global__ __launch_bounds__(256) void kan_build_wt(
    const float* __restrict__ sw,        // [OUTF][INF][11]
    const float* __restrict__ bw,        // [OUTF][INF]
    unsigned short* __restrict__ Wt)     // [OUTF][KTOT] bf16
{
  int idx = blockIdx.x * 256 + threadIdx.x;
  int o = idx >> 10;
  int i = idx & 1023;
  const float* s = sw + (size_t)(o * 1024 + i) * 11;
  unsigned short v[12];
#pragma unroll
  for (int l = 0; l < 11; ++l) v[l] = f2bf(s[l]);
  v[11] = f2bf(bw[o * 1024 + i]);
  unsigned short* d = Wt + (size_t)o * KTOT + i * 12;
  *reinterpret_cast<ushort4*>(d + 0) = make_ushort4(v[0], v[1], v[2],  v[3]);
  *reinterpret_cast<ushort4*>(d + 4) = make_ushort4(v[4], v[5], v[6],  v[7]);
  *reinterpret_cast<ushort4*>(d + 8) = make_ushort4(v[8], v[9], v[10], v[11]);
}

// ------- kernel 2: fused basis-build + MFMA GEMM (R3 schedule, granule-A) ----
__global__ __launch_bounds__(THREADS, 1) void kan_gemm(
    const float* __restrict__ x,             // [BATCH][INF]
    const unsigned short* __restrict__ Wt,   // [OUTF][KTOT] bf16
    float* __restrict__ out)                 // [BATCH][OUTF]
{
  // all 5 buffers in granule-interleaved layout [kk][row/col][8]
  __shared__ alignas(16) unsigned short smem[5 * BUFSZ];   // 122880 B

  const int tid  = threadIdx.x;
  const int lane = tid & 63;
  const int wid  = tid >> 6;              // 0..7
  const int wm   = (wid >> 1) * 32;       // 4 wave-rows of 32
  const int wn   = (wid & 1) * 64;        // 2 wave-cols of 64
  const int bm   = (int)blockIdx.x >> 3;  // 0..31
  const int bn   = (int)blockIdx.x & 7;   // 0..7
  const int lr   = lane & 15;
  const int lk   = lane >> 4;

  // A-build mapping: thread -> (row ab, 2 features at ai0); lane-consecutive rows
  const int ab  = tid & 127;
  const int ai0 = (tid >> 7) << 1;        // 0,2,4,6 (wave-uniform)
  const float* xrow = x + (size_t)(bm * BM + ab) * INF + ai0;

  unsigned short* Bcur = smem;
  unsigned short* Bnxt = smem + BUFSZ;
  unsigned short* Bnn  = smem + 2 * BUFSZ;
  unsigned short* Acur = smem + 3 * BUFSZ;
  unsigned short* Aalt = smem + 4 * BUFSZ;

  f32x4 acc[2][4] = {};

  auto stageB = [&](int c, unsigned short* Bd) {
#pragma unroll
    for (int qq = 0; qq < 3; ++qq) {
      int G  = (wid * 3 + qq) * 64 + lane;   // granule 0..1535 (linear dest, DMA rule)
      int kk = G >> 7;                       // 0..11
      int oo = G & 127;
      const unsigned short* src = Wt + (size_t)(bn * BN + oo) * KTOT + (c * BK + kk * 8);
      async_copy16(src, Bd + (wid * 3 + qq) * 512);   // wave-uniform base; HW adds lane*16
    }
  };

  auto buildA = [&](float2 xv, unsigned short* Ad) {
    ull W[6];
#pragma unroll
    for (int j = 0; j < 2; ++j) {
      float xx = (j == 0) ? xv.x : xv.y;
      float u  = fmaf(xx, 4.0f, 7.0f);       // in (3,11); x in (-1,1)
      float fm = floorf(u);
      int   mi = (int)fm;                    // 3..10
      float t  = u - fm;
      float s  = 1.0f - t;
      float t2 = t * t, t3 = t2 * t;
      float w0 = (s * s * s) * (1.0f / 6.0f);
      float w3 = t3 * (1.0f / 6.0f);
      float w1 = fmaf(0.5f, t3, 2.0f / 3.0f) - t2;
      float w2 = 1.0f - w0 - w1 - w3;
      int ls = mi - 3;                       // 0..7

      ull W64 = (ull)f2bf(w0)
              | ((ull)f2bf(w1) << 16)
              | ((ull)f2bf(w2) << 32)
              | ((ull)f2bf(w3) << 48);
      int sh = ls << 4;                      // 0..112
      int a  = sh & 63;
      ull lop  = W64 << a;
      ull hip_ = a ? (W64 >> (64 - a)) : 0ull;
      W[3 * j + 0] = (sh < 64) ? lop : 0ull;
      W[3 * j + 1] = (sh < 64) ? hip_ : lop;
      W[3 * j + 2] = ((sh < 64) ? 0ull : hip_) | ((ull)f2bf(xx) << 48); // slot 11 = x
    }
    // 3 granule-plane writes, lane-consecutive 16B -> conflict-free
    U2* p = reinterpret_cast<U2*>(Ad);
    const int g0 = (ai0 >> 1) * 3;           // 0,3,6,9
    U2 u0; u0.x = W[0]; u0.y = W[1];
    U2 u1; u1.x = W[2]; u1.y = W[3];
    U2 u2; u2.x = W[4]; u2.y = W[5];
    p[(g0 + 0) * 128 + ab] = u0;
    p[(g0 + 1) * 128 + ab] = u1;
    p[(g0 + 2) * 128 + ab] = u2;
  };

  // ---- prologue ----
  float2 x0v = *reinterpret_cast<const float2*>(xrow);        // chunk 0
  stageB(0, Bcur);
  buildA(x0v, Acur);
  float2 xa = *reinterpret_cast<const float2*>(xrow + IC);    // chunk 1
  stageB(1, Bnxt);
  PIPE_BARRIER();   // drains B0 DMAs + A0 writes; keeps {xa, B1 DMAs} in flight

  for (int c = 0; c < NCHUNK; ++c) {
    int cf = (c + 2 < NCHUNK) ? (c + 2) : (NCHUNK - 1);
    float2 xb = *reinterpret_cast<const float2*>(xrow + cf * IC);
    stageB(cf, Bnn);
    buildA(xa, Aalt);          // chunk c+1 basis

    // ---- MFMA: 3 k-steps of 32 (16x16x32), granule-addressed A and B ----
#pragma unroll
    for (int kk32 = 0; kk32 < 3; ++kk32) {
      bf16x8 af[2], bfr[4];
#pragma unroll
      for (int mf = 0; mf < 2; ++mf)
        af[mf] = *reinterpret_cast<const bf16x8*>(
            &Acur[(((kk32 * 4 + lk) * 128) + (wm + mf * 16 + lr)) * 8]);
#pragma unroll
      for (int nf = 0; nf < 4; ++nf)
        bfr[nf] = *reinterpret_cast<const bf16x8*>(
            &Bcur[(((kk32 * 4 + lk) * 128) + (wn + nf * 16 + lr)) * 8]);
#pragma unroll
      for (int mf = 0; mf < 2; ++mf)
#pragma unroll
        for (int nf = 0; nf < 4; ++nf)
          acc[mf][nf] = __builtin_amdgcn_mfma_f32_16x16x32_bf16(
              af[mf], bfr[nf], acc[mf][nf], 0, 0, 0);
    }

    PIPE_BARRIER();

    unsigned short* t = Bcur; Bcur = Bnxt; Bnxt = Bnn; Bnn = t;
    t = Acur; Acur = Aalt; Aalt = t;
    xa = xb;
  }

  // ---- epilogue ----
#pragma unroll
  for (int mf = 0; mf < 2; ++mf) {
#pragma unroll
    for (int v = 0; v < 4; ++v) {
      int row = bm * BM + wm + mf * 16 + lk * 4 + v;
      float* orow = out + (size_t)row * OUTF + bn * BN + wn + lr;
#pragma unroll
      for (int nf = 0; nf < 4; ++nf)
        orow[nf * 16] = acc[mf][nf][v];
    }
  }
}

extern "C" void kernel_launch(void* const* d_in, const int* in_sizes, int n_in,
                              void* d_out, int out_size, void* d_ws, size_t ws_size,
                              hipStream_t stream) {
  const float* x  = (const float*)d_in[0];   // [4096][1024]
  const float* bw = (const float*)d_in[1];   // [1024][1024]
  const float* sw = (const float*)d_in[2];   // [1024][1024][11]
  float* out = (float*)d_out;

  unsigned short* Wt = (unsigned short*)d_ws;
  if (ws_size < (size_t)OUTF * KTOT * sizeof(unsigned short)) return;

  kan_build_wt<<<(OUTF * INF) / 256, 256, 0, stream>>>(sw, bw, Wt);
  kan_gemm<<<(BATCH / BM) * (OUTF / BN), THREADS, 0, stream>>>(x, Wt, out);
}